// Round 8
// baseline (589.167 us; speedup 1.0000x reference)
//
#include <hip/hip_runtime.h>
#include <hip/hip_bf16.h>
#include <hip/hip_cooperative_groups.h>

namespace cg = cooperative_groups;

// Problem constants
#define NUM_NODES 500000
#define DD  128
#define UU  32
#define TT  4
#define AA  32
#define NSRC 65536
#define BB  8192
#define EE  262144                  // = 2^18
#define NEDGE (TT * EE)             // 2^20
#define NBKT (BB * TT)              // 32768 buckets, id = dst*4 + t
#define AGG_FLOATS (BB * TT * UU)   // 1,048,576 floats = 4 MB
#define NB  16                      // output nodes per node-phase block task
#define NSEG 512                    // scan segments (64 counters each)

__device__ __forceinline__ unsigned short f2bf(float f) {
    unsigned int u = __float_as_uint(f);
    unsigned int r = (u + 0x7FFFu + ((u >> 16) & 1u)) >> 16;   // RTNE
    return (unsigned short)r;
}

// ===================== fused cooperative kernel ==========================
__global__ __launch_bounds__(256) void fused_kernel(
    const float* __restrict__ node_emb,       // [NUM_NODES][D]
    const float4* __restrict__ nte4,          // [NUM_NODES][32] float4
    const float* __restrict__ w,              // [T][U][D]
    const float* __restrict__ s1,             // [T][U][A]
    const float* __restrict__ s2,             // [T][A]
    const int* __restrict__ input_nodes,      // [NSRC]
    const int* __restrict__ output_nodes,     // [B]
    const int* __restrict__ edge_src,         // [T*E]
    const int* __restrict__ edge_dst,         // [T*E]
    float* __restrict__ agg,                  // [B][T][U] f32
    unsigned short* __restrict__ feats,       // [T][NSRC][32] bf16
    int* __restrict__ cnt,
    int* __restrict__ base,
    int* __restrict__ cursor,
    int* __restrict__ segSum,
    int* __restrict__ segBase,
    int* __restrict__ sortedSrc,
    float* __restrict__ out)                  // [B][T][D]
{
    __shared__ float s_nte[NB][TT * UU];   // node phase (8 KB)
    __shared__ float s_comb[NB][UU];
    __shared__ float s_sc[NB][TT];
    __shared__ int   s_node[NB];

    cg::grid_group grid = cg::this_grid();
    const int NT = gridDim.x * 256;
    const int g  = blockIdx.x * 256 + threadIdx.x;

    // ---- Phase 0: zero counters + build bf16 per-type feature slices ----
    for (int i = g; i < NBKT; i += NT) cnt[i] = 0;
    for (int i = g; i < TT * NSRC * 8; i += NT) {
        int src = i >> 5, t = (i >> 3) & 3, q = i & 7;
        long node = input_nodes[src];
        float4 v = nte4[node * 32 + t * 8 + q];
        ushort4 o;
        o.x = f2bf(v.x); o.y = f2bf(v.y); o.z = f2bf(v.z); o.w = f2bf(v.w);
        *(ushort4*)(feats + (((size_t)t * NSRC + src) << 5) + (q << 2)) = o;
    }
    __threadfence(); grid.sync();

    // ---- Phase 1: histogram of (dst,t) ----
    for (int i = g; i < NEDGE; i += NT)
        atomicAdd(&cnt[edge_dst[i] * 4 + (i >> 18)], 1);
    __threadfence(); grid.sync();

    // ---- Phase 2a: per-segment sums ----
    for (int s = g; s < NSEG; s += NT) {
        int sum = 0;
        for (int j = 0; j < 64; ++j) sum += cnt[s * 64 + j];
        segSum[s] = sum;
    }
    __threadfence(); grid.sync();

    // ---- Phase 2b: scan the 512 segment sums (one wave) ----
    if (blockIdx.x == 0 && threadIdx.x < 64) {
        int lane = threadIdx.x;
        int v[8]; int tot = 0;
        #pragma unroll
        for (int r = 0; r < 8; ++r) { v[r] = segSum[lane * 8 + r]; tot += v[r]; }
        int inc = tot;
        #pragma unroll
        for (int d = 1; d < 64; d <<= 1) {
            int o = __shfl_up(inc, d, 64);
            if (lane >= d) inc += o;
        }
        int run = inc - tot;   // exclusive prefix of this lane's chunk
        #pragma unroll
        for (int r = 0; r < 8; ++r) { segBase[lane * 8 + r] = run; run += v[r]; }
    }
    __threadfence(); grid.sync();

    // ---- Phase 2c: expand to per-bucket base & cursor ----
    for (int s = g; s < NSEG; s += NT) {
        int run = segBase[s];
        for (int j = 0; j < 64; ++j) {
            int k = s * 64 + j;
            base[k] = run; cursor[k] = run; run += cnt[k];
        }
    }
    __threadfence(); grid.sync();

    // ---- Phase 3: scatter edges into buckets ----
    for (int i = g; i < NEDGE; i += NT) {
        int t = i >> 18;
        int pos = atomicAdd(&cursor[edge_dst[i] * 4 + t], 1);
        sortedSrc[pos] = edge_src[i];
    }
    __threadfence(); grid.sync();

    // ---- Phase 4: gather, wave per bucket (t-major for L2 locality) ----
    {
        int waveId = g >> 6, lane = threadIdx.x & 63;
        int nWaves = NT >> 6;
        int e8 = lane >> 3, q = lane & 7;
        for (int kp = waveId; kp < NBKT; kp += nWaves) {
            int t = kp >> 13, dst = kp & (BB - 1);
            int k = dst * 4 + t;
            int start = base[k], n = cnt[k];
            int pre = min(n, 64);
            int idx = sortedSrc[min(start + lane, NEDGE - 1)];  // coalesced preload
            const uint2* rows = (const uint2*)(feats + ((size_t)t * NSRC << 5)) + q;
            float a0 = 0.f, a1 = 0.f, a2 = 0.f, a3 = 0.f;
            int nIter = (pre + 7) >> 3;   // wave-uniform: shfl sources stay active
            for (int it = 0; it < nIter; ++it) {
                int j = (it << 3) + e8;
                int s = __shfl(idx, j, 64);
                if (j < pre) {
                    uint2 vv = rows[(size_t)s * 8];
                    a0 += __uint_as_float(vv.x << 16);
                    a1 += __uint_as_float(vv.x & 0xffff0000u);
                    a2 += __uint_as_float(vv.y << 16);
                    a3 += __uint_as_float(vv.y & 0xffff0000u);
                }
            }
            for (int j = 64 + e8; j < n; j += 8) {   // rare tail, direct loads
                int s = sortedSrc[start + j];
                uint2 vv = rows[(size_t)s * 8];
                a0 += __uint_as_float(vv.x << 16);
                a1 += __uint_as_float(vv.x & 0xffff0000u);
                a2 += __uint_as_float(vv.y << 16);
                a3 += __uint_as_float(vv.y & 0xffff0000u);
            }
            #pragma unroll
            for (int m = 8; m < 64; m <<= 1) {
                a0 += __shfl_xor(a0, m, 64);
                a1 += __shfl_xor(a1, m, 64);
                a2 += __shfl_xor(a2, m, 64);
                a3 += __shfl_xor(a3, m, 64);
            }
            if (lane < 8) ((float4*)agg)[k * 8 + lane] = make_float4(a0, a1, a2, a3);
        }
    }
    __threadfence(); grid.sync();

    // ---- Phase 5: per-output-node attention + transform + normalize ----
    {
        int tid  = threadIdx.x;
        int wv   = tid >> 6;
        int lane = tid & 63;
        for (int task = blockIdx.x; task < BB / NB; task += gridDim.x) {
            int b0 = task * NB;
            {
                const float4* av = (const float4*)(agg + b0 * 128);
                float4* sv = (float4*)&s_nte[0][0];
                sv[tid]       = av[tid];
                sv[tid + 256] = av[tid + 256];
            }
            if (tid < NB) s_node[tid] = output_nodes[b0 + tid];
            __syncthreads();

            int a  = lane & 31;
            int th = lane >> 5;
            int t0 = th, t1 = th + 2;
            float s1a[UU], s1b[UU];
            #pragma unroll
            for (int u = 0; u < UU; ++u) {
                s1a[u] = s1[(t0 * UU + u) * AA + a];
                s1b[u] = s1[(t1 * UU + u) * AA + a];
            }
            float s2a = s2[t0 * AA + a];
            float s2b = s2[t1 * AA + a];

            #pragma unroll
            for (int qq = 0; qq < 4; ++qq) {
                int bl = wv * 4 + qq;
                float acc0 = 0.f, acc1 = 0.f;
                #pragma unroll
                for (int u = 0; u < UU; ++u) {
                    acc0 += s_nte[bl][t0 * UU + u] * s1a[u];
                    acc1 += s_nte[bl][t1 * UU + u] * s1b[u];
                }
                float p0 = tanhf(acc0) * s2a;
                float p1 = tanhf(acc1) * s2b;
                #pragma unroll
                for (int m = 1; m < 32; m <<= 1) {
                    p0 += __shfl_xor(p0, m, 64);
                    p1 += __shfl_xor(p1, m, 64);
                }
                if ((lane & 31) == 0) { s_sc[bl][th] = p0; s_sc[bl][th + 2] = p1; }
            }
            __syncthreads();

            #pragma unroll
            for (int qq = 0; qq < 4; ++qq) {
                int bl = wv * 4 + qq;
                float sc0 = s_sc[bl][0], sc1 = s_sc[bl][1];
                float sc2 = s_sc[bl][2], sc3 = s_sc[bl][3];
                float mx = fmaxf(fmaxf(sc0, sc1), fmaxf(sc2, sc3));
                float e0 = expf(sc0 - mx), e1 = expf(sc1 - mx);
                float e2 = expf(sc2 - mx), e3 = expf(sc3 - mx);
                float isum = 1.f / (e0 + e1 + e2 + e3);
                if (lane < 32) {
                    float c = e0 * isum * s_nte[bl][a]
                            + e1 * isum * s_nte[bl][UU + a]
                            + e2 * isum * s_nte[bl][2 * UU + a]
                            + e3 * isum * s_nte[bl][3 * UU + a];
                    s_comb[bl][a] = c;
                }
            }
            __syncthreads();

            int t = wv;
            const float* wt = w + t * (UU * DD);
            float wA[UU], wB[UU];
            #pragma unroll
            for (int u = 0; u < UU; ++u) {
                wA[u] = wt[u * DD + lane];
                wB[u] = wt[u * DD + lane + 64];
            }
            for (int bl = 0; bl < NB; ++bl) {
                int node = s_node[bl];
                float accA = node_emb[(long)node * DD + lane];
                float accB = node_emb[(long)node * DD + lane + 64];
                #pragma unroll
                for (int u = 0; u < UU; ++u) {
                    float c = s_comb[bl][u];
                    accA += c * wA[u];
                    accB += c * wB[u];
                }
                float sq = accA * accA + accB * accB;
                #pragma unroll
                for (int m = 1; m < 64; m <<= 1)
                    sq += __shfl_xor(sq, m, 64);
                float invn = 1.f / fmaxf(sqrtf(sq), 1e-12f);
                int ob = (b0 + bl) * (TT * DD) + t * DD;
                out[ob + lane]      = accA * invn;
                out[ob + lane + 64] = accB * invn;
            }
            __syncthreads();   // protect shared reuse on next task
        }
    }
}

// ===================== fallback path (proven R2 structure) ===============
__global__ __launch_bounds__(256) void zero_agg_kernel(float4* __restrict__ p) {
    int i = blockIdx.x * 256 + threadIdx.x;
    p[i] = make_float4(0.f, 0.f, 0.f, 0.f);
}

__global__ __launch_bounds__(256) void edge_atomic_kernel(
    const float* __restrict__ nte_in,
    const int* __restrict__ input_nodes,
    const int* __restrict__ edge_src,
    const int* __restrict__ edge_dst,
    float* __restrict__ agg)
{
    int tid = blockIdx.x * 256 + threadIdx.x;
    int i = tid >> 5;
    int u = tid & 31;
    int t = i >> 18;
    int src = edge_src[i];
    int dst = edge_dst[i];
    int node = input_nodes[src];
    float v = nte_in[(long)node * 128 + t * 32 + u];
    atomicAdd(&agg[dst * 128 + t * 32 + u], v);
}

__global__ __launch_bounds__(256) void node_kernel(
    const float* __restrict__ node_emb,
    const float* __restrict__ w,
    const float* __restrict__ s1,
    const float* __restrict__ s2,
    const int* __restrict__ output_nodes,
    const float* __restrict__ agg,
    float* __restrict__ out)
{
    __shared__ float s_nte[NB][TT * UU];
    __shared__ float s_comb[NB][UU];
    __shared__ float s_sc[NB][TT];
    __shared__ int   s_node[NB];

    int tid  = threadIdx.x;
    int wv   = tid >> 6;
    int lane = tid & 63;
    int b0   = blockIdx.x * NB;

    {
        const float4* av = (const float4*)(agg + b0 * 128);
        float4* sv = (float4*)&s_nte[0][0];
        sv[tid]       = av[tid];
        sv[tid + 256] = av[tid + 256];
    }
    if (tid < NB) s_node[tid] = output_nodes[b0 + tid];
    __syncthreads();

    int a  = lane & 31;
    int th = lane >> 5;
    int t0 = th, t1 = th + 2;
    float s1a[UU], s1b[UU];
    #pragma unroll
    for (int u = 0; u < UU; ++u) {
        s1a[u] = s1[(t0 * UU + u) * AA + a];
        s1b[u] = s1[(t1 * UU + u) * AA + a];
    }
    float s2a = s2[t0 * AA + a];
    float s2b = s2[t1 * AA + a];

    #pragma unroll
    for (int q = 0; q < 4; ++q) {
        int bl = wv * 4 + q;
        float acc0 = 0.f, acc1 = 0.f;
        #pragma unroll
        for (int u = 0; u < UU; ++u) {
            acc0 += s_nte[bl][t0 * UU + u] * s1a[u];
            acc1 += s_nte[bl][t1 * UU + u] * s1b[u];
        }
        float p0 = tanhf(acc0) * s2a;
        float p1 = tanhf(acc1) * s2b;
        #pragma unroll
        for (int m = 1; m < 32; m <<= 1) {
            p0 += __shfl_xor(p0, m, 64);
            p1 += __shfl_xor(p1, m, 64);
        }
        if ((lane & 31) == 0) { s_sc[bl][th] = p0; s_sc[bl][th + 2] = p1; }
    }
    __syncthreads();

    #pragma unroll
    for (int q = 0; q < 4; ++q) {
        int bl = wv * 4 + q;
        float sc0 = s_sc[bl][0], sc1 = s_sc[bl][1];
        float sc2 = s_sc[bl][2], sc3 = s_sc[bl][3];
        float mx = fmaxf(fmaxf(sc0, sc1), fmaxf(sc2, sc3));
        float e0 = expf(sc0 - mx), e1 = expf(sc1 - mx);
        float e2 = expf(sc2 - mx), e3 = expf(sc3 - mx);
        float isum = 1.f / (e0 + e1 + e2 + e3);
        if (lane < 32) {
            float c = e0 * isum * s_nte[bl][a]
                    + e1 * isum * s_nte[bl][UU + a]
                    + e2 * isum * s_nte[bl][2 * UU + a]
                    + e3 * isum * s_nte[bl][3 * UU + a];
            s_comb[bl][a] = c;
        }
    }
    __syncthreads();

    int t = wv;
    const float* wt = w + t * (UU * DD);
    float wA[UU], wB[UU];
    #pragma unroll
    for (int u = 0; u < UU; ++u) {
        wA[u] = wt[u * DD + lane];
        wB[u] = wt[u * DD + lane + 64];
    }
    for (int bl = 0; bl < NB; ++bl) {
        int node = s_node[bl];
        float accA = node_emb[(long)node * DD + lane];
        float accB = node_emb[(long)node * DD + lane + 64];
        #pragma unroll
        for (int u = 0; u < UU; ++u) {
            float c = s_comb[bl][u];
            accA += c * wA[u];
            accB += c * wB[u];
        }
        float sq = accA * accA + accB * accB;
        #pragma unroll
        for (int m = 1; m < 64; m <<= 1)
            sq += __shfl_xor(sq, m, 64);
        float invn = 1.f / fmaxf(sqrtf(sq), 1e-12f);
        int ob = (b0 + bl) * (TT * DD) + t * DD;
        out[ob + lane]      = accA * invn;
        out[ob + lane + 64] = accB * invn;
    }
}

// =========================================================================
extern "C" void kernel_launch(void* const* d_in, const int* in_sizes, int n_in,
                              void* d_out, int out_size, void* d_ws, size_t ws_size,
                              hipStream_t stream) {
    const float* node_emb = (const float*)d_in[0];
    const float* nte_in   = (const float*)d_in[1];
    const float* w        = (const float*)d_in[2];
    const float* s1       = (const float*)d_in[3];
    const float* s2       = (const float*)d_in[4];
    const int* input_nodes  = (const int*)d_in[5];
    const int* output_nodes = (const int*)d_in[6];
    const int* edge_src     = (const int*)d_in[7];
    const int* edge_dst     = (const int*)d_in[8];
    float* out = (float*)d_out;

    // workspace layout
    char* ws = (char*)d_ws;
    float*          agg   = (float*)ws;                                   // 4 MB
    unsigned short* feats = (unsigned short*)(ws + (size_t)AGG_FLOATS*4); // 16 MB
    char* p2 = ws + (size_t)AGG_FLOATS*4 + (size_t)TT*NSRC*32*2;
    int* cnt       = (int*)p2;
    int* base      = cnt + NBKT;
    int* cursor    = base + NBKT;
    int* segSum    = cursor + NBKT;
    int* segBase   = segSum + NSEG;
    int* sortedSrc = segBase + NSEG;                                      // 4 MB
    size_t need = (size_t)AGG_FLOATS*4 + (size_t)TT*NSRC*32*2
                + (3u*NBKT + 2u*NSEG)*4 + (size_t)NEDGE*4;

    bool launched = false;
    if (ws_size >= need) {
        int dev = 0;
        hipGetDevice(&dev);
        int numCU = 0;
        hipDeviceGetAttribute(&numCU, hipDeviceAttributeMultiprocessorCount, dev);
        int maxBlk = 0;
        hipOccupancyMaxActiveBlocksPerMultiprocessor(&maxBlk, fused_kernel, 256, 0);
        if (numCU > 0 && maxBlk > 0) {
            int G = numCU * maxBlk;
            if (G > 2048) G = 2048;
            const float4* nte4 = (const float4*)nte_in;
            void* args[] = {
                (void*)&node_emb, (void*)&nte4, (void*)&w, (void*)&s1, (void*)&s2,
                (void*)&input_nodes, (void*)&output_nodes,
                (void*)&edge_src, (void*)&edge_dst,
                (void*)&agg, (void*)&feats,
                (void*)&cnt, (void*)&base, (void*)&cursor,
                (void*)&segSum, (void*)&segBase, (void*)&sortedSrc,
                (void*)&out
            };
            hipError_t e = hipLaunchCooperativeKernel(fused_kernel, dim3(G), dim3(256),
                                                      args, 0, stream);
            launched = (e == hipSuccess);
        }
    }

    if (!launched) {
        // fallback: proven direct-atomic 3-kernel path
        zero_agg_kernel<<<dim3(AGG_FLOATS / 4 / 256), dim3(256), 0, stream>>>((float4*)agg);
        edge_atomic_kernel<<<dim3((NEDGE * 32) / 256), dim3(256), 0, stream>>>(
            nte_in, input_nodes, edge_src, edge_dst, agg);
        node_kernel<<<dim3(BB / NB), dim3(256), 0, stream>>>(
            node_emb, w, s1, s2, output_nodes, agg, out);
    }
}

// Round 9
// 133.071 us; speedup vs baseline: 4.4275x; 4.4275x over previous
//
#include <hip/hip_runtime.h>
#include <hip/hip_bf16.h>

// Problem constants
#define NUM_NODES 500000
#define DD  128
#define UU  32
#define TT  4
#define AA  32
#define NSRC 65536
#define BB  8192
#define EE  262144                  // = 2^18
#define NEDGE (TT * EE)             // 2^20
#define NBKT (BB * TT)              // 32768 buckets, id = dst*4 + t
#define CAP 128                     // slots per bucket (mean 32; P(overflow)~0)
#define AGG_FLOATS (BB * TT * UU)
#define NB  16                      // output nodes per block in gather+node

__device__ __forceinline__ unsigned short f2bf(float f) {
    unsigned int u = __float_as_uint(f);
    unsigned int r = (u + 0x7FFFu + ((u >> 16) & 1u)) >> 16;   // RTNE
    return (unsigned short)r;
}

// ---- K1: zero counters (blocks 0..31) + build bf16 feats (rest) ---------
__global__ __launch_bounds__(256) void prep_kernel(
    const float4* __restrict__ nte4,         // [NUM_NODES][32] float4
    const int* __restrict__ input_nodes,     // [NSRC]
    unsigned short* __restrict__ feats,      // [T][NSRC][32] bf16
    int* __restrict__ cnt,                   // [NBKT]
    int* __restrict__ ovfCnt)
{
    int b = blockIdx.x;
    if (b < 32) {
        int i = b * 256 + threadIdx.x;       // 8192 int4 = NBKT ints
        ((int4*)cnt)[i] = make_int4(0, 0, 0, 0);
        if (b == 0 && threadIdx.x == 0) *ovfCnt = 0;
        return;
    }
    int gtid = (b - 32) * 256 + threadIdx.x; // T*NSRC*8 = 2M
    int src = gtid >> 5;
    int t = (gtid >> 3) & 3;
    int q = gtid & 7;
    long node = input_nodes[src];
    float4 v = nte4[node * 32 + t * 8 + q];
    ushort4 o;
    o.x = f2bf(v.x); o.y = f2bf(v.y); o.z = f2bf(v.z); o.w = f2bf(v.w);
    *(ushort4*)(feats + (((size_t)t * NSRC + src) << 5) + (q << 2)) = o;
}

// ---- K2: place each edge's src into its bucket's slot array -------------
__global__ __launch_bounds__(256) void place_kernel(
    const int* __restrict__ edge_src,
    const int* __restrict__ edge_dst,
    int* __restrict__ cnt,
    int* __restrict__ slots,                 // [NBKT][CAP]
    int* __restrict__ ovfCnt,
    int* __restrict__ ovf)                   // [NEDGE][2] worst case
{
    int i = blockIdx.x * 256 + threadIdx.x;  // edge id
    int k = edge_dst[i] * 4 + (i >> 18);
    int src = edge_src[i];
    int pos = atomicAdd(&cnt[k], 1);
    if (pos < CAP) {
        slots[k * CAP + pos] = src;
    } else {                                  // essentially never
        int o = atomicAdd(ovfCnt, 1);
        ovf[2 * o] = k; ovf[2 * o + 1] = src;
    }
}

// ---- K3: gather buckets into LDS + attention + transform + normalize ----
__global__ __launch_bounds__(256) void gather_node_kernel(
    const unsigned short* __restrict__ feats,  // [T][NSRC][32] bf16
    const int* __restrict__ slots,
    const int* __restrict__ cnt,
    const int* __restrict__ ovf,
    const int* __restrict__ ovfCnt,
    const float* __restrict__ node_emb,        // [NUM_NODES][D]
    const float* __restrict__ w,               // [T][U][D]
    const float* __restrict__ s1,              // [T][U][A]
    const float* __restrict__ s2,              // [T][A]
    const int* __restrict__ output_nodes,      // [B]
    float* __restrict__ out)                   // [B][T][D]
{
    __shared__ float s_nte[NB][TT * UU];   // 8 KB
    __shared__ float s_comb[NB][UU];
    __shared__ float s_sc[NB][TT];
    __shared__ int   s_node[NB];
    __shared__ int   s_ovf;

    int tid  = threadIdx.x;
    int wv   = tid >> 6;
    int lane = tid & 63;
    int b0   = blockIdx.x * NB;
    int e8 = lane >> 3, q = lane & 7;

    // ---- gather: wave wv covers dst bl = wv*4+qq, all 4 t ----
    #pragma unroll
    for (int qq = 0; qq < 4; ++qq) {
        int bl = wv * 4 + qq;
        int dst = b0 + bl;
        #pragma unroll
        for (int t = 0; t < 4; ++t) {
            int k = dst * 4 + t;
            int n = cnt[k];
            int nslot = min(n, CAP);
            int pre = min(nslot, 64);
            int idx = slots[k * CAP + lane];   // coalesced; garbage beyond nslot guarded below
            const uint2* rows = (const uint2*)(feats + ((size_t)t * NSRC << 5)) + q;
            float a0 = 0.f, a1 = 0.f, a2 = 0.f, a3 = 0.f;
            int nIter = (pre + 7) >> 3;        // wave-uniform: shfl sources stay active
            for (int it = 0; it < nIter; ++it) {
                int j = (it << 3) + e8;
                int s = __shfl(idx, j, 64);
                if (j < pre) {
                    uint2 vv = rows[(size_t)s * 8];
                    a0 += __uint_as_float(vv.x << 16);
                    a1 += __uint_as_float(vv.x & 0xffff0000u);
                    a2 += __uint_as_float(vv.y << 16);
                    a3 += __uint_as_float(vv.y & 0xffff0000u);
                }
            }
            for (int j = 64 + e8; j < nslot; j += 8) {   // rare (n>64), direct loads
                int s = slots[k * CAP + j];
                uint2 vv = rows[(size_t)s * 8];
                a0 += __uint_as_float(vv.x << 16);
                a1 += __uint_as_float(vv.x & 0xffff0000u);
                a2 += __uint_as_float(vv.y << 16);
                a3 += __uint_as_float(vv.y & 0xffff0000u);
            }
            #pragma unroll
            for (int m = 8; m < 64; m <<= 1) {
                a0 += __shfl_xor(a0, m, 64);
                a1 += __shfl_xor(a1, m, 64);
                a2 += __shfl_xor(a2, m, 64);
                a3 += __shfl_xor(a3, m, 64);
            }
            if (lane < 8)
                ((float4*)&s_nte[bl][t * 32])[lane] = make_float4(a0, a1, a2, a3);
        }
    }
    if (tid < NB) s_node[tid] = output_nodes[b0 + tid];
    if (tid == 0) s_ovf = *ovfCnt;
    __syncthreads();

    // ---- overflow fix-up (never executes in practice; correctness only) ----
    if (s_ovf > 0) {
        for (int r = tid; r < s_ovf; r += 256) {
            int k = ovf[2 * r];
            int dst = k >> 2;
            if (dst >= b0 && dst < b0 + NB) {
                int src = ovf[2 * r + 1];
                int t = k & 3, bl = dst - b0;
                const unsigned short* row = feats + (((size_t)t * NSRC + src) << 5);
                for (int u = 0; u < UU; ++u)
                    atomicAdd(&s_nte[bl][t * 32 + u],
                              __uint_as_float((unsigned)row[u] << 16));
            }
        }
        __syncthreads();
    }

    // ---- Phase A: attention scores ----
    int a  = lane & 31;
    int th = lane >> 5;
    int t0 = th, t1 = th + 2;
    float s1a[UU], s1b[UU];
    #pragma unroll
    for (int u = 0; u < UU; ++u) {
        s1a[u] = s1[(t0 * UU + u) * AA + a];
        s1b[u] = s1[(t1 * UU + u) * AA + a];
    }
    float s2a = s2[t0 * AA + a];
    float s2b = s2[t1 * AA + a];

    #pragma unroll
    for (int qq = 0; qq < 4; ++qq) {
        int bl = wv * 4 + qq;
        float acc0 = 0.f, acc1 = 0.f;
        #pragma unroll
        for (int u = 0; u < UU; ++u) {
            acc0 += s_nte[bl][t0 * UU + u] * s1a[u];
            acc1 += s_nte[bl][t1 * UU + u] * s1b[u];
        }
        float p0 = tanhf(acc0) * s2a;
        float p1 = tanhf(acc1) * s2b;
        #pragma unroll
        for (int m = 1; m < 32; m <<= 1) {
            p0 += __shfl_xor(p0, m, 64);
            p1 += __shfl_xor(p1, m, 64);
        }
        if ((lane & 31) == 0) { s_sc[bl][th] = p0; s_sc[bl][th + 2] = p1; }
    }
    __syncthreads();

    #pragma unroll
    for (int qq = 0; qq < 4; ++qq) {
        int bl = wv * 4 + qq;
        float sc0 = s_sc[bl][0], sc1 = s_sc[bl][1];
        float sc2 = s_sc[bl][2], sc3 = s_sc[bl][3];
        float mx = fmaxf(fmaxf(sc0, sc1), fmaxf(sc2, sc3));
        float e0 = expf(sc0 - mx), e1 = expf(sc1 - mx);
        float e2 = expf(sc2 - mx), e3 = expf(sc3 - mx);
        float isum = 1.f / (e0 + e1 + e2 + e3);
        if (lane < 32) {
            float c = e0 * isum * s_nte[bl][a]
                    + e1 * isum * s_nte[bl][UU + a]
                    + e2 * isum * s_nte[bl][2 * UU + a]
                    + e3 * isum * s_nte[bl][3 * UU + a];
            s_comb[bl][a] = c;
        }
    }
    __syncthreads();

    // ---- Phase B: transform + add emb + normalize; wave == t ----
    int t = wv;
    const float* wt = w + t * (UU * DD);
    float wA[UU], wB[UU];
    #pragma unroll
    for (int u = 0; u < UU; ++u) {
        wA[u] = wt[u * DD + lane];
        wB[u] = wt[u * DD + lane + 64];
    }
    for (int bl = 0; bl < NB; ++bl) {
        int node = s_node[bl];
        float accA = node_emb[(long)node * DD + lane];
        float accB = node_emb[(long)node * DD + lane + 64];
        #pragma unroll
        for (int u = 0; u < UU; ++u) {
            float c = s_comb[bl][u];
            accA += c * wA[u];
            accB += c * wB[u];
        }
        float sq = accA * accA + accB * accB;
        #pragma unroll
        for (int m = 1; m < 64; m <<= 1)
            sq += __shfl_xor(sq, m, 64);
        float invn = 1.f / fmaxf(sqrtf(sq), 1e-12f);
        int ob = (b0 + bl) * (TT * DD) + t * DD;
        out[ob + lane]      = accA * invn;
        out[ob + lane + 64] = accB * invn;
    }
}

// ===================== fallback path (proven R2 structure) ===============
__global__ __launch_bounds__(256) void zero_agg_kernel(float4* __restrict__ p) {
    int i = blockIdx.x * 256 + threadIdx.x;
    p[i] = make_float4(0.f, 0.f, 0.f, 0.f);
}

__global__ __launch_bounds__(256) void edge_atomic_kernel(
    const float* __restrict__ nte_in,
    const int* __restrict__ input_nodes,
    const int* __restrict__ edge_src,
    const int* __restrict__ edge_dst,
    float* __restrict__ agg)
{
    int tid = blockIdx.x * 256 + threadIdx.x;
    int i = tid >> 5;
    int u = tid & 31;
    int t = i >> 18;
    int src = edge_src[i];
    int dst = edge_dst[i];
    int node = input_nodes[src];
    float v = nte_in[(long)node * 128 + t * 32 + u];
    atomicAdd(&agg[dst * 128 + t * 32 + u], v);
}

__global__ __launch_bounds__(256) void node_kernel(
    const float* __restrict__ node_emb,
    const float* __restrict__ w,
    const float* __restrict__ s1,
    const float* __restrict__ s2,
    const int* __restrict__ output_nodes,
    const float* __restrict__ agg,
    float* __restrict__ out)
{
    __shared__ float s_nte[NB][TT * UU];
    __shared__ float s_comb[NB][UU];
    __shared__ float s_sc[NB][TT];
    __shared__ int   s_node[NB];

    int tid  = threadIdx.x;
    int wv   = tid >> 6;
    int lane = tid & 63;
    int b0   = blockIdx.x * NB;

    {
        const float4* av = (const float4*)(agg + b0 * 128);
        float4* sv = (float4*)&s_nte[0][0];
        sv[tid]       = av[tid];
        sv[tid + 256] = av[tid + 256];
    }
    if (tid < NB) s_node[tid] = output_nodes[b0 + tid];
    __syncthreads();

    int a  = lane & 31;
    int th = lane >> 5;
    int t0 = th, t1 = th + 2;
    float s1a[UU], s1b[UU];
    #pragma unroll
    for (int u = 0; u < UU; ++u) {
        s1a[u] = s1[(t0 * UU + u) * AA + a];
        s1b[u] = s1[(t1 * UU + u) * AA + a];
    }
    float s2a = s2[t0 * AA + a];
    float s2b = s2[t1 * AA + a];

    #pragma unroll
    for (int q = 0; q < 4; ++q) {
        int bl = wv * 4 + q;
        float acc0 = 0.f, acc1 = 0.f;
        #pragma unroll
        for (int u = 0; u < UU; ++u) {
            acc0 += s_nte[bl][t0 * UU + u] * s1a[u];
            acc1 += s_nte[bl][t1 * UU + u] * s1b[u];
        }
        float p0 = tanhf(acc0) * s2a;
        float p1 = tanhf(acc1) * s2b;
        #pragma unroll
        for (int m = 1; m < 32; m <<= 1) {
            p0 += __shfl_xor(p0, m, 64);
            p1 += __shfl_xor(p1, m, 64);
        }
        if ((lane & 31) == 0) { s_sc[bl][th] = p0; s_sc[bl][th + 2] = p1; }
    }
    __syncthreads();

    #pragma unroll
    for (int q = 0; q < 4; ++q) {
        int bl = wv * 4 + q;
        float sc0 = s_sc[bl][0], sc1 = s_sc[bl][1];
        float sc2 = s_sc[bl][2], sc3 = s_sc[bl][3];
        float mx = fmaxf(fmaxf(sc0, sc1), fmaxf(sc2, sc3));
        float e0 = expf(sc0 - mx), e1 = expf(sc1 - mx);
        float e2 = expf(sc2 - mx), e3 = expf(sc3 - mx);
        float isum = 1.f / (e0 + e1 + e2 + e3);
        if (lane < 32) {
            float c = e0 * isum * s_nte[bl][a]
                    + e1 * isum * s_nte[bl][UU + a]
                    + e2 * isum * s_nte[bl][2 * UU + a]
                    + e3 * isum * s_nte[bl][3 * UU + a];
            s_comb[bl][a] = c;
        }
    }
    __syncthreads();

    int t = wv;
    const float* wt = w + t * (UU * DD);
    float wA[UU], wB[UU];
    #pragma unroll
    for (int u = 0; u < UU; ++u) {
        wA[u] = wt[u * DD + lane];
        wB[u] = wt[u * DD + lane + 64];
    }
    for (int bl = 0; bl < NB; ++bl) {
        int node = s_node[bl];
        float accA = node_emb[(long)node * DD + lane];
        float accB = node_emb[(long)node * DD + lane + 64];
        #pragma unroll
        for (int u = 0; u < UU; ++u) {
            float c = s_comb[bl][u];
            accA += c * wA[u];
            accB += c * wB[u];
        }
        float sq = accA * accA + accB * accB;
        #pragma unroll
        for (int m = 1; m < 64; m <<= 1)
            sq += __shfl_xor(sq, m, 64);
        float invn = 1.f / fmaxf(sqrtf(sq), 1e-12f);
        int ob = (b0 + bl) * (TT * DD) + t * DD;
        out[ob + lane]      = accA * invn;
        out[ob + lane + 64] = accB * invn;
    }
}

// =========================================================================
extern "C" void kernel_launch(void* const* d_in, const int* in_sizes, int n_in,
                              void* d_out, int out_size, void* d_ws, size_t ws_size,
                              hipStream_t stream) {
    const float* node_emb = (const float*)d_in[0];
    const float* nte_in   = (const float*)d_in[1];
    const float* w        = (const float*)d_in[2];
    const float* s1       = (const float*)d_in[3];
    const float* s2       = (const float*)d_in[4];
    const int* input_nodes  = (const int*)d_in[5];
    const int* output_nodes = (const int*)d_in[6];
    const int* edge_src     = (const int*)d_in[7];
    const int* edge_dst     = (const int*)d_in[8];
    float* out = (float*)d_out;

    // workspace layout (main path)
    char* ws = (char*)d_ws;
    unsigned short* feats = (unsigned short*)ws;                      // 16 MB
    size_t off = (size_t)TT * NSRC * 32 * 2;
    int* slots  = (int*)(ws + off);          off += (size_t)NBKT * CAP * 4;  // 16 MB
    int* cnt    = (int*)(ws + off);          off += (size_t)NBKT * 4;        // 128 KB
    int* ovfCnt = (int*)(ws + off);          off += 256;
    int* ovf    = (int*)(ws + off);          off += (size_t)NEDGE * 2 * 4;   // 8 MB
    size_t need = off;

    if (ws_size >= need) {
        prep_kernel<<<dim3(32 + TT * NSRC * 8 / 256), dim3(256), 0, stream>>>(
            (const float4*)nte_in, input_nodes, feats, cnt, ovfCnt);
        place_kernel<<<dim3(NEDGE / 256), dim3(256), 0, stream>>>(
            edge_src, edge_dst, cnt, slots, ovfCnt, ovf);
        gather_node_kernel<<<dim3(BB / NB), dim3(256), 0, stream>>>(
            feats, slots, cnt, ovf, ovfCnt,
            node_emb, w, s1, s2, output_nodes, out);
    } else {
        // fallback: proven direct-atomic 3-kernel path
        float* agg = (float*)d_ws;   // 4 MB
        zero_agg_kernel<<<dim3(AGG_FLOATS / 4 / 256), dim3(256), 0, stream>>>((float4*)agg);
        edge_atomic_kernel<<<dim3((NEDGE * 32) / 256), dim3(256), 0, stream>>>(
            nte_in, input_nodes, edge_src, edge_dst, agg);
        node_kernel<<<dim3(BB / NB), dim3(256), 0, stream>>>(
            node_emb, w, s1, s2, output_nodes, agg, out);
    }
}

// Round 10
// 116.650 us; speedup vs baseline: 5.0507x; 1.1408x over previous
//
#include <hip/hip_runtime.h>
#include <hip/hip_bf16.h>

// Problem constants
#define NUM_NODES 500000
#define DD  128
#define UU  32
#define TT  4
#define AA  32
#define NSRC 65536
#define BB  8192
#define EE  262144                  // = 2^18
#define NEDGE (TT * EE)             // 2^20
#define NBKT (BB * TT)              // 32768 buckets, id = dst*4 + t
#define CAP 128                     // slots per bucket (mean 32; P(overflow)~0)
#define AGG_FLOATS (BB * TT * UU)
#define NB  16                      // output nodes per block in gather+node

__device__ __forceinline__ unsigned short f2bf(float f) {
    unsigned int u = __float_as_uint(f);
    unsigned int r = (u + 0x7FFFu + ((u >> 16) & 1u)) >> 16;   // RTNE
    return (unsigned short)r;
}

// ---- K1: zero counters (blocks 0..31) + build bf16 feats (rest) ---------
__global__ __launch_bounds__(256) void prep_kernel(
    const float4* __restrict__ nte4,         // [NUM_NODES][32] float4
    const int* __restrict__ input_nodes,     // [NSRC]
    unsigned short* __restrict__ feats,      // [T][NSRC][32] bf16
    int* __restrict__ cnt,                   // [NBKT]
    int* __restrict__ ovfCnt)
{
    int b = blockIdx.x;
    if (b < 32) {
        int i = b * 256 + threadIdx.x;       // 8192 int4 = NBKT ints
        ((int4*)cnt)[i] = make_int4(0, 0, 0, 0);
        if (b == 0 && threadIdx.x == 0) *ovfCnt = 0;
        return;
    }
    int gtid = (b - 32) * 256 + threadIdx.x; // T*NSRC*8 = 2M
    int src = gtid >> 5;
    int t = (gtid >> 3) & 3;
    int q = gtid & 7;
    long node = input_nodes[src];
    float4 v = nte4[node * 32 + t * 8 + q];
    ushort4 o;
    o.x = f2bf(v.x); o.y = f2bf(v.y); o.z = f2bf(v.z); o.w = f2bf(v.w);
    *(ushort4*)(feats + (((size_t)t * NSRC + src) << 5) + (q << 2)) = o;
}

// ---- K2: place each edge's src into its bucket's slot array -------------
__global__ __launch_bounds__(256) void place_kernel(
    const int* __restrict__ edge_src,
    const int* __restrict__ edge_dst,
    int* __restrict__ cnt,
    int* __restrict__ slots,                 // [NBKT][CAP]
    int* __restrict__ ovfCnt,
    int* __restrict__ ovf)                   // [NEDGE][2] worst case
{
    int i = blockIdx.x * 256 + threadIdx.x;  // edge id
    int k = edge_dst[i] * 4 + (i >> 18);
    int src = edge_src[i];
    int pos = atomicAdd(&cnt[k], 1);
    if (pos < CAP) {
        slots[k * CAP + pos] = src;
    } else {                                  // essentially never
        int o = atomicAdd(ovfCnt, 1);
        ovf[2 * o] = k; ovf[2 * o + 1] = src;
    }
}

// ---- K3: gather buckets into LDS + attention + transform + normalize ----
// 1024 threads = 16 waves; wave wv gathers dst b0+wv (its 4 t-buckets).
__global__ __launch_bounds__(1024) void gather_node_kernel(
    const unsigned short* __restrict__ feats,  // [T][NSRC][32] bf16
    const int* __restrict__ slots,
    const int* __restrict__ cnt,
    const int* __restrict__ ovf,
    const int* __restrict__ ovfCnt,
    const float* __restrict__ node_emb,        // [NUM_NODES][D]
    const float* __restrict__ w,               // [T][U][D]
    const float* __restrict__ s1,              // [T][U][A]
    const float* __restrict__ s2,              // [T][A]
    const int* __restrict__ output_nodes,      // [B]
    float* __restrict__ out)                   // [B][T][D]
{
    __shared__ float s_nte[NB][TT * UU];   // 8 KB
    __shared__ float s_comb[NB][UU];
    __shared__ float s_sc[NB][TT];
    __shared__ int   s_node[NB];
    __shared__ int   s_ovf;

    int tid  = threadIdx.x;
    int wv   = tid >> 6;                   // 0..15
    int lane = tid & 63;
    int b0   = blockIdx.x * NB;
    int e8 = lane >> 3, q = lane & 7;

    // ---- gather: wave wv covers dst b0+wv, all 4 t (4 independent chains)
    {
        int dst = b0 + wv;
        #pragma unroll
        for (int t = 0; t < 4; ++t) {
            int k = dst * 4 + t;
            int n = cnt[k];
            int nslot = min(n, CAP);
            int pre = min(nslot, 64);
            int idx = slots[k * CAP + lane];   // coalesced; use guarded by j<pre
            const uint2* rows = (const uint2*)(feats + ((size_t)t * NSRC << 5)) + q;
            float a0 = 0.f, a1 = 0.f, a2 = 0.f, a3 = 0.f;
            int nIter = (pre + 7) >> 3;        // wave-uniform: shfl sources stay active
            for (int it = 0; it < nIter; ++it) {
                int j = (it << 3) + e8;
                int s = __shfl(idx, j, 64);
                if (j < pre) {
                    uint2 vv = rows[(size_t)s * 8];
                    a0 += __uint_as_float(vv.x << 16);
                    a1 += __uint_as_float(vv.x & 0xffff0000u);
                    a2 += __uint_as_float(vv.y << 16);
                    a3 += __uint_as_float(vv.y & 0xffff0000u);
                }
            }
            for (int j = 64 + e8; j < nslot; j += 8) {   // rare (n>64), direct loads
                int s = slots[k * CAP + j];
                uint2 vv = rows[(size_t)s * 8];
                a0 += __uint_as_float(vv.x << 16);
                a1 += __uint_as_float(vv.x & 0xffff0000u);
                a2 += __uint_as_float(vv.y << 16);
                a3 += __uint_as_float(vv.y & 0xffff0000u);
            }
            #pragma unroll
            for (int m = 8; m < 64; m <<= 1) {
                a0 += __shfl_xor(a0, m, 64);
                a1 += __shfl_xor(a1, m, 64);
                a2 += __shfl_xor(a2, m, 64);
                a3 += __shfl_xor(a3, m, 64);
            }
            if (lane < 8)
                ((float4*)&s_nte[wv][t * 32])[lane] = make_float4(a0, a1, a2, a3);
        }
    }
    if (tid < NB) s_node[tid] = output_nodes[b0 + tid];
    if (tid == 0) s_ovf = *ovfCnt;
    __syncthreads();

    // ---- overflow fix-up (never executes in practice; correctness only) ----
    if (s_ovf > 0) {
        for (int r = tid; r < s_ovf; r += 1024) {
            int k = ovf[2 * r];
            int dst = k >> 2;
            if (dst >= b0 && dst < b0 + NB) {
                int src = ovf[2 * r + 1];
                int t = k & 3, bl = dst - b0;
                const unsigned short* row = feats + (((size_t)t * NSRC + src) << 5);
                for (int u = 0; u < UU; ++u)
                    atomicAdd(&s_nte[bl][t * 32 + u],
                              __uint_as_float((unsigned)row[u] << 16));
            }
        }
        __syncthreads();
    }

    // ---- Phase A: attention scores; wave wv handles bl = wv ----
    int a  = lane & 31;
    int th = lane >> 5;
    int t0 = th, t1 = th + 2;
    {
        int bl = wv;
        float acc0 = 0.f, acc1 = 0.f;
        #pragma unroll
        for (int u = 0; u < UU; ++u) {
            acc0 += s_nte[bl][t0 * UU + u] * s1[(t0 * UU + u) * AA + a];
            acc1 += s_nte[bl][t1 * UU + u] * s1[(t1 * UU + u) * AA + a];
        }
        float p0 = tanhf(acc0) * s2[t0 * AA + a];
        float p1 = tanhf(acc1) * s2[t1 * AA + a];
        #pragma unroll
        for (int m = 1; m < 32; m <<= 1) {
            p0 += __shfl_xor(p0, m, 64);
            p1 += __shfl_xor(p1, m, 64);
        }
        if ((lane & 31) == 0) { s_sc[bl][th] = p0; s_sc[bl][th + 2] = p1; }
    }
    __syncthreads();

    // softmax + combined; wave wv handles bl = wv
    {
        int bl = wv;
        float sc0 = s_sc[bl][0], sc1 = s_sc[bl][1];
        float sc2 = s_sc[bl][2], sc3 = s_sc[bl][3];
        float mx = fmaxf(fmaxf(sc0, sc1), fmaxf(sc2, sc3));
        float e0 = expf(sc0 - mx), e1 = expf(sc1 - mx);
        float e2 = expf(sc2 - mx), e3 = expf(sc3 - mx);
        float isum = 1.f / (e0 + e1 + e2 + e3);
        if (lane < 32) {
            float c = e0 * isum * s_nte[bl][a]
                    + e1 * isum * s_nte[bl][UU + a]
                    + e2 * isum * s_nte[bl][2 * UU + a]
                    + e3 * isum * s_nte[bl][3 * UU + a];
            s_comb[bl][a] = c;
        }
    }
    __syncthreads();

    // ---- Phase B: wave = (t, group); each wave does 4 bl's ----
    int t   = wv & 3;
    int grp = wv >> 2;
    const float* wt = w + t * (UU * DD);
    float wA[UU], wB[UU];
    #pragma unroll
    for (int u = 0; u < UU; ++u) {
        wA[u] = wt[u * DD + lane];
        wB[u] = wt[u * DD + lane + 64];
    }
    #pragma unroll
    for (int j = 0; j < 4; ++j) {
        int bl = grp * 4 + j;
        int node = s_node[bl];
        float accA = node_emb[(long)node * DD + lane];
        float accB = node_emb[(long)node * DD + lane + 64];
        #pragma unroll
        for (int u = 0; u < UU; ++u) {
            float c = s_comb[bl][u];
            accA += c * wA[u];
            accB += c * wB[u];
        }
        float sq = accA * accA + accB * accB;
        #pragma unroll
        for (int m = 1; m < 64; m <<= 1)
            sq += __shfl_xor(sq, m, 64);
        float invn = 1.f / fmaxf(sqrtf(sq), 1e-12f);
        int ob = (b0 + bl) * (TT * DD) + t * DD;
        out[ob + lane]      = accA * invn;
        out[ob + lane + 64] = accB * invn;
    }
}

// ===================== fallback path (proven R2 structure) ===============
__global__ __launch_bounds__(256) void zero_agg_kernel(float4* __restrict__ p) {
    int i = blockIdx.x * 256 + threadIdx.x;
    p[i] = make_float4(0.f, 0.f, 0.f, 0.f);
}

__global__ __launch_bounds__(256) void edge_atomic_kernel(
    const float* __restrict__ nte_in,
    const int* __restrict__ input_nodes,
    const int* __restrict__ edge_src,
    const int* __restrict__ edge_dst,
    float* __restrict__ agg)
{
    int tid = blockIdx.x * 256 + threadIdx.x;
    int i = tid >> 5;
    int u = tid & 31;
    int t = i >> 18;
    int src = edge_src[i];
    int dst = edge_dst[i];
    int node = input_nodes[src];
    float v = nte_in[(long)node * 128 + t * 32 + u];
    atomicAdd(&agg[dst * 128 + t * 32 + u], v);
}

__global__ __launch_bounds__(256) void node_kernel(
    const float* __restrict__ node_emb,
    const float* __restrict__ w,
    const float* __restrict__ s1,
    const float* __restrict__ s2,
    const int* __restrict__ output_nodes,
    const float* __restrict__ agg,
    float* __restrict__ out)
{
    __shared__ float s_nte[NB][TT * UU];
    __shared__ float s_comb[NB][UU];
    __shared__ float s_sc[NB][TT];
    __shared__ int   s_node[NB];

    int tid  = threadIdx.x;
    int wv   = tid >> 6;
    int lane = tid & 63;
    int b0   = blockIdx.x * NB;

    {
        const float4* av = (const float4*)(agg + b0 * 128);
        float4* sv = (float4*)&s_nte[0][0];
        sv[tid]       = av[tid];
        sv[tid + 256] = av[tid + 256];
    }
    if (tid < NB) s_node[tid] = output_nodes[b0 + tid];
    __syncthreads();

    int a  = lane & 31;
    int th = lane >> 5;
    int t0 = th, t1 = th + 2;
    float s1a[UU], s1b[UU];
    #pragma unroll
    for (int u = 0; u < UU; ++u) {
        s1a[u] = s1[(t0 * UU + u) * AA + a];
        s1b[u] = s1[(t1 * UU + u) * AA + a];
    }
    float s2a = s2[t0 * AA + a];
    float s2b = s2[t1 * AA + a];

    #pragma unroll
    for (int q = 0; q < 4; ++q) {
        int bl = wv * 4 + q;
        float acc0 = 0.f, acc1 = 0.f;
        #pragma unroll
        for (int u = 0; u < UU; ++u) {
            acc0 += s_nte[bl][t0 * UU + u] * s1a[u];
            acc1 += s_nte[bl][t1 * UU + u] * s1b[u];
        }
        float p0 = tanhf(acc0) * s2a;
        float p1 = tanhf(acc1) * s2b;
        #pragma unroll
        for (int m = 1; m < 32; m <<= 1) {
            p0 += __shfl_xor(p0, m, 64);
            p1 += __shfl_xor(p1, m, 64);
        }
        if ((lane & 31) == 0) { s_sc[bl][th] = p0; s_sc[bl][th + 2] = p1; }
    }
    __syncthreads();

    #pragma unroll
    for (int q = 0; q < 4; ++q) {
        int bl = wv * 4 + q;
        float sc0 = s_sc[bl][0], sc1 = s_sc[bl][1];
        float sc2 = s_sc[bl][2], sc3 = s_sc[bl][3];
        float mx = fmaxf(fmaxf(sc0, sc1), fmaxf(sc2, sc3));
        float e0 = expf(sc0 - mx), e1 = expf(sc1 - mx);
        float e2 = expf(sc2 - mx), e3 = expf(sc3 - mx);
        float isum = 1.f / (e0 + e1 + e2 + e3);
        if (lane < 32) {
            float c = e0 * isum * s_nte[bl][a]
                    + e1 * isum * s_nte[bl][UU + a]
                    + e2 * isum * s_nte[bl][2 * UU + a]
                    + e3 * isum * s_nte[bl][3 * UU + a];
            s_comb[bl][a] = c;
        }
    }
    __syncthreads();

    int t = wv;
    const float* wt = w + t * (UU * DD);
    float wA[UU], wB[UU];
    #pragma unroll
    for (int u = 0; u < UU; ++u) {
        wA[u] = wt[u * DD + lane];
        wB[u] = wt[u * DD + lane + 64];
    }
    for (int bl = 0; bl < NB; ++bl) {
        int node = s_node[bl];
        float accA = node_emb[(long)node * DD + lane];
        float accB = node_emb[(long)node * DD + lane + 64];
        #pragma unroll
        for (int u = 0; u < UU; ++u) {
            float c = s_comb[bl][u];
            accA += c * wA[u];
            accB += c * wB[u];
        }
        float sq = accA * accA + accB * accB;
        #pragma unroll
        for (int m = 1; m < 64; m <<= 1)
            sq += __shfl_xor(sq, m, 64);
        float invn = 1.f / fmaxf(sqrtf(sq), 1e-12f);
        int ob = (b0 + bl) * (TT * DD) + t * DD;
        out[ob + lane]      = accA * invn;
        out[ob + lane + 64] = accB * invn;
    }
}

// =========================================================================
extern "C" void kernel_launch(void* const* d_in, const int* in_sizes, int n_in,
                              void* d_out, int out_size, void* d_ws, size_t ws_size,
                              hipStream_t stream) {
    const float* node_emb = (const float*)d_in[0];
    const float* nte_in   = (const float*)d_in[1];
    const float* w        = (const float*)d_in[2];
    const float* s1       = (const float*)d_in[3];
    const float* s2       = (const float*)d_in[4];
    const int* input_nodes  = (const int*)d_in[5];
    const int* output_nodes = (const int*)d_in[6];
    const int* edge_src     = (const int*)d_in[7];
    const int* edge_dst     = (const int*)d_in[8];
    float* out = (float*)d_out;

    // workspace layout (main path)
    char* ws = (char*)d_ws;
    unsigned short* feats = (unsigned short*)ws;                      // 16 MB
    size_t off = (size_t)TT * NSRC * 32 * 2;
    int* slots  = (int*)(ws + off);          off += (size_t)NBKT * CAP * 4;  // 16 MB
    int* cnt    = (int*)(ws + off);          off += (size_t)NBKT * 4;        // 128 KB
    int* ovfCnt = (int*)(ws + off);          off += 256;
    int* ovf    = (int*)(ws + off);          off += (size_t)NEDGE * 2 * 4;   // 8 MB
    size_t need = off;

    if (ws_size >= need) {
        prep_kernel<<<dim3(32 + TT * NSRC * 8 / 256), dim3(256), 0, stream>>>(
            (const float4*)nte_in, input_nodes, feats, cnt, ovfCnt);
        place_kernel<<<dim3(NEDGE / 256), dim3(256), 0, stream>>>(
            edge_src, edge_dst, cnt, slots, ovfCnt, ovf);
        gather_node_kernel<<<dim3(BB / NB), dim3(1024), 0, stream>>>(
            feats, slots, cnt, ovf, ovfCnt,
            node_emb, w, s1, s2, output_nodes, out);
    } else {
        // fallback: proven direct-atomic 3-kernel path
        float* agg = (float*)d_ws;   // 4 MB
        zero_agg_kernel<<<dim3(AGG_FLOATS / 4 / 256), dim3(256), 0, stream>>>((float4*)agg);
        edge_atomic_kernel<<<dim3((NEDGE * 32) / 256), dim3(256), 0, stream>>>(
            nte_in, input_nodes, edge_src, edge_dst, agg);
        node_kernel<<<dim3(BB / NB), dim3(256), 0, stream>>>(
            node_emb, w, s1, s2, output_nodes, agg, out);
    }
}